// Round 11
// baseline (29.980 us; speedup 1.0000x reference)
//
#include <hip/hip_runtime.h>

#define EPSF 1e-6f
#define TPB 256
#define KMAXC 21           // seg channels (K = 21)
#define NGR 21             // gt rows staged
#define RW 72              // bf16 row stride per wave slice (144 B; 16B-aligned frags)
#define SLICE (KMAXC * RW) // 1512 bf16 per matrix per wave
#define TBL 1024           // 32x32 cells per per-block table (4 KB stride)
#define MAXBLK 1200

typedef float  f32x4  __attribute__((ext_vector_type(4)));
typedef float  f32x16 __attribute__((ext_vector_type(16)));
typedef __bf16 bf16x8 __attribute__((ext_vector_type(8)));
typedef __bf16 bf16x4 __attribute__((ext_vector_type(4)));

struct GroupRegs { f32x4 s[6]; int4 g[6]; };

// issue all 12 vector loads for one 64-pixel group (stay in flight together)
__device__ __forceinline__ void issue_loads(const float* __restrict__ seg,
                                            const int* __restrict__ gt,
                                            int N, int GROWS, int p0, int lane,
                                            GroupRegs& r) {
    const f32x4* s4 = (const f32x4*)(seg + (size_t)p0 * KMAXC);
    #pragma unroll
    for (int q = 0; q < 6; ++q) {
        const int i4 = lane + (q << 6);            // f32x4 idx in [0,336)
        f32x4 v = {0.5f, 0.5f, 0.5f, 0.5f};
        if (i4 < 336) v = s4[i4];
        r.s[q] = v;
    }
    #pragma unroll
    for (int q = 0; q < 6; ++q) {
        const int i4 = lane + (q << 6);
        int4 gv = {0, 0, 0, 0};
        if (i4 < 336) {
            int row = i4 >> 4;                     // 0..20 (16 int4 per row)
            row = (row < GROWS) ? row : (GROWS - 1);
            gv = *(const int4*)(gt + (size_t)row * N + p0 + ((i4 & 15) << 2));
        }
        r.g[q] = gv;
    }
}

// log-odds + bf16 scatter to this wave's LDS slice
__device__ __forceinline__ void scatter_group(__bf16* dl, __bf16* ml, int lane,
                                              const GroupRegs& r) {
    #pragma unroll
    for (int q = 0; q < 6; ++q) {
        const int i4 = lane + (q << 6);
        if (i4 < 336) {
            const int lin = i4 << 2;
            int pix = lin / KMAXC;
            int k   = lin - pix * KMAXC;
            #pragma unroll
            for (int c = 0; c < 4; ++c) {
                const float s = r.s[q][c];
                const float dd = __log2f(s + EPSF) - __log2f(1.0f - s + EPSF);
                dl[k * RW + pix] = (__bf16)dd;
                if (++k == KMAXC) { k = 0; ++pix; }
            }
            const int row = i4 >> 4;
            bf16x4 mv;
            mv[0] = (__bf16)(float)(r.g[q].x != 0);
            mv[1] = (__bf16)(float)(r.g[q].y != 0);
            mv[2] = (__bf16)(float)(r.g[q].z != 0);
            mv[3] = (__bf16)(float)(r.g[q].w != 0);
            *(bf16x4*)(ml + row * RW + ((i4 & 15) << 2)) = mv;
        }
    }
}

// 4x MFMA over one 64-pixel group (K-dim = pixels)
__device__ __forceinline__ void mfma_group(const __bf16* dl, const __bf16* ml,
                                           int lane, int K, f32x16& acc) {
    const int r31  = lane & 31;
    const int rowA = (r31 < K)   ? r31 : (K - 1);   // clamp: dup rows discarded
    const int rowB = (r31 < NGR) ? r31 : (NGR - 1);
    const int off  = (lane >> 5) << 3;
    const __bf16* pa = dl + rowA * RW + off;
    const __bf16* pb = ml + rowB * RW + off;
    #pragma unroll
    for (int i = 0; i < 4; ++i) {
        const bf16x8 af = *(const bf16x8*)(pa + i * 16);
        const bf16x8 bf = *(const bf16x8*)(pb + i * 16);
        acc = __builtin_amdgcn_mfma_f32_32x32x16_bf16(af, bf, acc, 0, 0, 0);
    }
}

// generic per-element path (tail group / odd K)
__device__ __forceinline__ void generic_group(const float* __restrict__ seg,
                                              const int* __restrict__ gt,
                                              __bf16* dl, __bf16* ml, int lane,
                                              int N, int K, int GROWS, int p0) {
    for (int i = lane; i < K * 64; i += 64) {
        const int pix = i / K, k = i - pix * K;
        const float s = (p0 + pix < N) ? seg[(size_t)(p0 + pix) * K + k] : 0.5f;
        const float dd = __log2f(s + EPSF) - __log2f(1.0f - s + EPSF);
        if (k < KMAXC) dl[k * RW + pix] = (__bf16)dd;   // s=0.5 -> d=0 (inert)
    }
    for (int i = lane; i < NGR * 64; i += 64) {
        const int row = i >> 6, c = i & 63;
        int val = 0;
        if (row < GROWS && p0 + c < N) val = (gt[(size_t)row * N + p0 + c] != 0);
        ml[row * RW + c] = (__bf16)(float)val;
    }
}

// K1: A[k,g] = sum_n d[k,n]*gi[g,n]; wave-private; per-block private output
// table (no atom-RMW, no zero-init needed: every read cell written each call).
__global__ __launch_bounds__(TPB) void msk_main(
    const float* __restrict__ seg,   // (N, K) row-major
    const int* __restrict__ gt,      // (GROWS, N) row-major
    float* __restrict__ sums,        // NBLK x [TBL] f32 per-block tables
    int N, int K, int GROWS, int NGROUP, int NBLK)
{
    const int tid  = threadIdx.x;
    const int lane = tid & 63;
    const int wv   = tid >> 6;

    __shared__ union {
        __bf16 stage[4][2][SLICE];   // [wave][0=d rows [k][px], 1=mask rows [g][px]]
        float  red[4 * TBL];
    } u;

    f32x16 acc = {};
    __bf16* dl = u.stage[wv][0];
    __bf16* ml = u.stage[wv][1];

    const int W  = NBLK * 4;
    const int gw = (int)blockIdx.x * 4 + wv;

    if (K == KMAXC) {
        const int g0 = gw, g1 = gw + W;
        const bool f0 = (g0 < NGROUP) && ((g0 << 6) + 64 <= N);
        const bool f1 = (g1 < NGROUP) && ((g1 << 6) + 64 <= N);
        GroupRegs r0, r1;
        if (f0) issue_loads(seg, gt, N, GROWS, g0 << 6, lane, r0);
        if (f1) issue_loads(seg, gt, N, GROWS, g1 << 6, lane, r1);
        if (f0) { scatter_group(dl, ml, lane, r0); mfma_group(dl, ml, lane, K, acc); }
        if (f1) { scatter_group(dl, ml, lane, r1); mfma_group(dl, ml, lane, K, acc); }
        if (g0 < NGROUP && !f0) {
            generic_group(seg, gt, dl, ml, lane, N, K, GROWS, g0 << 6);
            mfma_group(dl, ml, lane, K, acc);
        }
        if (g1 < NGROUP && !f1) {
            generic_group(seg, gt, dl, ml, lane, N, K, GROWS, g1 << 6);
            mfma_group(dl, ml, lane, K, acc);
        }
        for (int gid = gw + 2 * W; gid < NGROUP; gid += W) {
            const int p0 = gid << 6;
            if (p0 + 64 <= N) {
                GroupRegs r;
                issue_loads(seg, gt, N, GROWS, p0, lane, r);
                scatter_group(dl, ml, lane, r);
            } else {
                generic_group(seg, gt, dl, ml, lane, N, K, GROWS, p0);
            }
            mfma_group(dl, ml, lane, K, acc);
        }
    } else {
        for (int gid = gw; gid < NGROUP; gid += W) {
            generic_group(seg, gt, dl, ml, lane, N, K, GROWS, gid << 6);
            mfma_group(dl, ml, lane, K, acc);
        }
    }

    // ---- cross-wave reduce via canonical LDS layout ----
    __syncthreads();
    {
        const int col = lane & 31;
        const int rhi = (lane >> 5) << 2;
        #pragma unroll
        for (int r = 0; r < 16; ++r) {
            const int row = (r & 3) + ((r >> 2) << 3) + rhi;   // verified C/D mapping
            u.red[wv * TBL + row * 32 + col] = acc[r];
        }
    }
    __syncthreads();

    // ---- private table write: live rows only (rows >= K never read by K2);
    //      relaxed agent-scope atomic stores (plain stores proved unsafe
    //      cross-kernel under graph replay) ----
    {
        float* stbl = sums + (size_t)blockIdx.x * TBL;
        const int live = K * 32;             // 672 cells
        for (int cell = tid; cell < live; cell += TPB) {
            const float v = u.red[cell] + u.red[TBL + cell]
                          + u.red[2 * TBL + cell] + u.red[3 * TBL + cell];
            __hip_atomic_store(&stbl[cell], v, __ATOMIC_RELAXED,
                               __HIP_MEMORY_SCOPE_AGENT);
        }
    }
}

// K2: block k reduces its row across all NBLK tables; 8 independent streams
// per thread -> dependency depth ceil(NBLK/256) instead of ~NBLK/64.
__global__ __launch_bounds__(1024) void msk_final(
    const float* __restrict__ sums,
    const int* __restrict__ gpn,
    int* __restrict__ out,
    int K, int NBLK)
{
    const int G = *gpn;
    const int k = blockIdx.x;
    const int tid = threadIdx.x;
    const int col = tid & 31;
    const int grp = tid >> 5;            // 0..31 table-groups

    float v0 = 0.f, v1 = 0.f, v2 = 0.f, v3 = 0.f;
    float v4 = 0.f, v5 = 0.f, v6 = 0.f, v7 = 0.f;
    const size_t rowoff = (size_t)k * 32 + col;

    for (int base = 0; base < NBLK; base += 256) {
        const int t0 = base + grp * 8;
        #define LD(S, ACC) do {                                              \
            const int t_ = t0 + (S);                                         \
            if (t_ < NBLK)                                                   \
                ACC += __hip_atomic_load(&sums[(size_t)t_ * TBL + rowoff],   \
                                         __ATOMIC_RELAXED,                   \
                                         __HIP_MEMORY_SCOPE_AGENT);          \
        } while (0)
        LD(0, v0); LD(1, v1); LD(2, v2); LD(3, v3);
        LD(4, v4); LD(5, v5); LD(6, v6); LD(7, v7);
        #undef LD
    }
    const float vv = ((v0 + v1) + (v2 + v3)) + ((v4 + v5) + (v6 + v7));

    __shared__ float P[32][33];
    __shared__ float A[32];
    P[grp][col] = vv;
    __syncthreads();
    if (tid < 32) {
        float s = 0.f;
        #pragma unroll
        for (int g2 = 0; g2 < 32; ++g2) s += P[g2][tid];
        A[tid] = s;
    }
    __syncthreads();

    if (tid == 0) {
        const int GG = (G < 32) ? G : 32;
        float bv; int bg = 0;
        if (GG > 0) {
            bv = A[0];
            for (int g = 1; g < GG; ++g) {
                const float v = A[g];
                if (v > bv) { bv = v; bg = g; }   // strict '>' keeps first index
            }
        }
        out[k] = bg;
    }
}

extern "C" void kernel_launch(void* const* d_in, const int* in_sizes, int n_in,
                              void* d_out, int out_size, void* d_ws, size_t ws_size,
                              hipStream_t stream) {
    const float* seg = (const float*)d_in[0];
    // d_in[1] (prob) does not affect the reference output
    const int* gt  = (const int*)d_in[2];
    const int* gpn = (const int*)d_in[3];

    const int N = in_sizes[1];              // prob is (N,1)
    const int K = in_sizes[0] / N;          // 21
    const int GROWS = in_sizes[2] / N;      // 21
    const int NGROUP = (N + 63) >> 6;       // 4800 64-px groups

    int NBLK = MAXBLK;                      // 1 group per wave at 1200 blocks
    const int minb = (NGROUP + 3) >> 2;
    if (NBLK > minb) NBLK = minb;
    const long long wcap = (long long)(ws_size / (TBL * sizeof(float)));
    if (NBLK > wcap) NBLK = (int)wcap;      // d_ws budget (observed ~256 MB)
    if (NBLK < 1) NBLK = 1;

    msk_main <<<NBLK, TPB, 0, stream>>>(seg, gt, (float*)d_ws,
                                        N, K, GROWS, NGROUP, NBLK);
    msk_final<<<K, 1024, 0, stream>>>((const float*)d_ws, gpn, (int*)d_out,
                                      K, NBLK);
}

// Round 12
// 22.644 us; speedup vs baseline: 1.3240x; 1.3240x over previous
//
#include <hip/hip_runtime.h>

#define EPSF 1e-6f
#define TPB 256
#define KMAXC 21           // seg channels (K = 21)
#define NGR 21             // gt rows staged
#define RW 72              // bf16 row stride per wave slice (144 B; 16B-aligned frags)
#define SLICE (KMAXC * RW) // 1512 bf16 per matrix per wave
#define TBL 1024           // 32x32 cells per per-block table (4 KB stride)
#define MAXBLK 1152        // 16 K2-groups x 72 tables (exact 8x9 stream tiling)

typedef float  f32x4  __attribute__((ext_vector_type(4)));
typedef float  f32x16 __attribute__((ext_vector_type(16)));
typedef __bf16 bf16x8 __attribute__((ext_vector_type(8)));
typedef __bf16 bf16x4 __attribute__((ext_vector_type(4)));

struct GroupRegs { f32x4 s[6]; int4 g[6]; };

// issue all 12 vector loads for one 64-pixel group (stay in flight together)
__device__ __forceinline__ void issue_loads(const float* __restrict__ seg,
                                            const int* __restrict__ gt,
                                            int N, int GROWS, int p0, int lane,
                                            GroupRegs& r) {
    const f32x4* s4 = (const f32x4*)(seg + (size_t)p0 * KMAXC);
    #pragma unroll
    for (int q = 0; q < 6; ++q) {
        const int i4 = lane + (q << 6);            // f32x4 idx in [0,336)
        f32x4 v = {0.5f, 0.5f, 0.5f, 0.5f};
        if (i4 < 336) v = s4[i4];
        r.s[q] = v;
    }
    #pragma unroll
    for (int q = 0; q < 6; ++q) {
        const int i4 = lane + (q << 6);
        int4 gv = {0, 0, 0, 0};
        if (i4 < 336) {
            int row = i4 >> 4;                     // 0..20 (16 int4 per row)
            row = (row < GROWS) ? row : (GROWS - 1);
            gv = *(const int4*)(gt + (size_t)row * N + p0 + ((i4 & 15) << 2));
        }
        r.g[q] = gv;
    }
}

// log-odds + bf16 scatter to this wave's LDS slice
__device__ __forceinline__ void scatter_group(__bf16* dl, __bf16* ml, int lane,
                                              const GroupRegs& r) {
    #pragma unroll
    for (int q = 0; q < 6; ++q) {
        const int i4 = lane + (q << 6);
        if (i4 < 336) {
            const int lin = i4 << 2;
            int pix = lin / KMAXC;
            int k   = lin - pix * KMAXC;
            #pragma unroll
            for (int c = 0; c < 4; ++c) {
                const float s = r.s[q][c];
                const float dd = __log2f(s + EPSF) - __log2f(1.0f - s + EPSF);
                dl[k * RW + pix] = (__bf16)dd;
                if (++k == KMAXC) { k = 0; ++pix; }
            }
            const int row = i4 >> 4;
            bf16x4 mv;
            mv[0] = (__bf16)(float)(r.g[q].x != 0);
            mv[1] = (__bf16)(float)(r.g[q].y != 0);
            mv[2] = (__bf16)(float)(r.g[q].z != 0);
            mv[3] = (__bf16)(float)(r.g[q].w != 0);
            *(bf16x4*)(ml + row * RW + ((i4 & 15) << 2)) = mv;
        }
    }
}

// 4x MFMA over one 64-pixel group (K-dim = pixels)
__device__ __forceinline__ void mfma_group(const __bf16* dl, const __bf16* ml,
                                           int lane, int K, f32x16& acc) {
    const int r31  = lane & 31;
    const int rowA = (r31 < K)   ? r31 : (K - 1);   // clamp: dup rows discarded
    const int rowB = (r31 < NGR) ? r31 : (NGR - 1);
    const int off  = (lane >> 5) << 3;
    const __bf16* pa = dl + rowA * RW + off;
    const __bf16* pb = ml + rowB * RW + off;
    #pragma unroll
    for (int i = 0; i < 4; ++i) {
        const bf16x8 af = *(const bf16x8*)(pa + i * 16);
        const bf16x8 bf = *(const bf16x8*)(pb + i * 16);
        acc = __builtin_amdgcn_mfma_f32_32x32x16_bf16(af, bf, acc, 0, 0, 0);
    }
}

// generic per-element path (tail group / odd K)
__device__ __forceinline__ void generic_group(const float* __restrict__ seg,
                                              const int* __restrict__ gt,
                                              __bf16* dl, __bf16* ml, int lane,
                                              int N, int K, int GROWS, int p0) {
    for (int i = lane; i < K * 64; i += 64) {
        const int pix = i / K, k = i - pix * K;
        const float s = (p0 + pix < N) ? seg[(size_t)(p0 + pix) * K + k] : 0.5f;
        const float dd = __log2f(s + EPSF) - __log2f(1.0f - s + EPSF);
        if (k < KMAXC) dl[k * RW + pix] = (__bf16)dd;   // s=0.5 -> d=0 (inert)
    }
    for (int i = lane; i < NGR * 64; i += 64) {
        const int row = i >> 6, c = i & 63;
        int val = 0;
        if (row < GROWS && p0 + c < N) val = (gt[(size_t)row * N + p0 + c] != 0);
        ml[row * RW + c] = (__bf16)(float)val;
    }
}

// K1: A[k,g] = sum_n d[k,n]*gi[g,n]; wave-private; per-block private output
// table (no atom-RMW, no zero-init needed: every read cell written each call).
__global__ __launch_bounds__(TPB) void msk_main(
    const float* __restrict__ seg,   // (N, K) row-major
    const int* __restrict__ gt,      // (GROWS, N) row-major
    float* __restrict__ sums,        // NBLK x [TBL] f32 per-block tables
    int N, int K, int GROWS, int NGROUP, int NBLK)
{
    const int tid  = threadIdx.x;
    const int lane = tid & 63;
    const int wv   = tid >> 6;

    __shared__ union {
        __bf16 stage[4][2][SLICE];   // [wave][0=d rows [k][px], 1=mask rows [g][px]]
        float  red[4 * TBL];
    } u;

    f32x16 acc = {};
    __bf16* dl = u.stage[wv][0];
    __bf16* ml = u.stage[wv][1];

    const int W  = NBLK * 4;
    const int gw = (int)blockIdx.x * 4 + wv;

    if (K == KMAXC) {
        const int g0 = gw, g1 = gw + W;
        const bool f0 = (g0 < NGROUP) && ((g0 << 6) + 64 <= N);
        const bool f1 = (g1 < NGROUP) && ((g1 << 6) + 64 <= N);
        GroupRegs r0, r1;
        if (f0) issue_loads(seg, gt, N, GROWS, g0 << 6, lane, r0);
        if (f1) issue_loads(seg, gt, N, GROWS, g1 << 6, lane, r1);
        if (f0) { scatter_group(dl, ml, lane, r0); mfma_group(dl, ml, lane, K, acc); }
        if (f1) { scatter_group(dl, ml, lane, r1); mfma_group(dl, ml, lane, K, acc); }
        if (g0 < NGROUP && !f0) {
            generic_group(seg, gt, dl, ml, lane, N, K, GROWS, g0 << 6);
            mfma_group(dl, ml, lane, K, acc);
        }
        if (g1 < NGROUP && !f1) {
            generic_group(seg, gt, dl, ml, lane, N, K, GROWS, g1 << 6);
            mfma_group(dl, ml, lane, K, acc);
        }
        for (int gid = gw + 2 * W; gid < NGROUP; gid += W) {
            const int p0 = gid << 6;
            if (p0 + 64 <= N) {
                GroupRegs r;
                issue_loads(seg, gt, N, GROWS, p0, lane, r);
                scatter_group(dl, ml, lane, r);
            } else {
                generic_group(seg, gt, dl, ml, lane, N, K, GROWS, p0);
            }
            mfma_group(dl, ml, lane, K, acc);
        }
    } else {
        for (int gid = gw; gid < NGROUP; gid += W) {
            generic_group(seg, gt, dl, ml, lane, N, K, GROWS, gid << 6);
            mfma_group(dl, ml, lane, K, acc);
        }
    }

    // ---- cross-wave reduce via canonical LDS layout ----
    __syncthreads();
    {
        const int col = lane & 31;
        const int rhi = (lane >> 5) << 2;
        #pragma unroll
        for (int r = 0; r < 16; ++r) {
            const int row = (r & 3) + ((r >> 2) << 3) + rhi;   // verified C/D mapping
            u.red[wv * TBL + row * 32 + col] = acc[r];
        }
    }
    __syncthreads();

    // ---- private table write: relaxed agent-scope atomic stores (coherent
    //      point; plain stores proved unsafe cross-kernel under graph replay) ----
    {
        float* stbl = sums + (size_t)blockIdx.x * TBL;
        #pragma unroll
        for (int q = 0; q < TBL / TPB; ++q) {
            const int cell = q * TPB + tid;
            const float v = u.red[cell] + u.red[TBL + cell]
                          + u.red[2 * TBL + cell] + u.red[3 * TBL + cell];
            __hip_atomic_store(&stbl[cell], v, __ATOMIC_RELAXED,
                               __HIP_MEMORY_SCOPE_AGENT);
        }
    }
}

// K2: block k reduces its row across all NBLK tables. 512 threads, 16 table-
// groups; each group owns a CONTIGUOUS run of NBLK/16 tables walked with 8
// independent accumulator streams and unconditional affine loads (depth
// NBLK/128 dependent rounds, 8 loads in flight each).
__global__ __launch_bounds__(512) void msk_final(
    const float* __restrict__ sums,
    const int* __restrict__ gpn,
    int* __restrict__ out,
    int K, int NBLK)
{
    const int G = *gpn;
    const int k = blockIdx.x;
    const int tid = threadIdx.x;
    const int col = tid & 31;
    const int grp = tid >> 5;            // 0..15 table-groups

    const int tpg = NBLK >> 4;           // tables per group (72 at NBLK=1152)
    const int t0  = grp * tpg;
    const size_t rowoff = (size_t)k * 32 + col;

    #define AL(T) __hip_atomic_load(&sums[(size_t)(T) * TBL + rowoff], \
                                    __ATOMIC_RELAXED, __HIP_MEMORY_SCOPE_AGENT)
    float v0 = 0.f, v1 = 0.f, v2 = 0.f, v3 = 0.f;
    float v4 = 0.f, v5 = 0.f, v6 = 0.f, v7 = 0.f;
    int i = 0;
    for (; i + 8 <= tpg; i += 8) {       // unconditional: 8 loads in flight
        v0 += AL(t0 + i + 0); v1 += AL(t0 + i + 1);
        v2 += AL(t0 + i + 2); v3 += AL(t0 + i + 3);
        v4 += AL(t0 + i + 4); v5 += AL(t0 + i + 5);
        v6 += AL(t0 + i + 6); v7 += AL(t0 + i + 7);
    }
    for (; i < tpg; ++i) v0 += AL(t0 + i);
    // leftover tables beyond 16*tpg (NBLK % 16 of them)
    if (grp < (NBLK & 15)) v1 += AL((NBLK & ~15) + grp);
    #undef AL
    const float vv = ((v0 + v1) + (v2 + v3)) + ((v4 + v5) + (v6 + v7));

    __shared__ float P[16][33];
    __shared__ float A[32];
    P[grp][col] = vv;
    __syncthreads();
    if (tid < 32) {
        float s = 0.f;
        #pragma unroll
        for (int g2 = 0; g2 < 16; ++g2) s += P[g2][tid];
        A[tid] = s;
    }
    __syncthreads();

    if (tid == 0) {
        const int GG = (G < 32) ? G : 32;
        float bv; int bg = 0;
        if (GG > 0) {
            bv = A[0];
            for (int g = 1; g < GG; ++g) {
                const float v = A[g];
                if (v > bv) { bv = v; bg = g; }   // strict '>' keeps first index
            }
        }
        out[k] = bg;
    }
}

extern "C" void kernel_launch(void* const* d_in, const int* in_sizes, int n_in,
                              void* d_out, int out_size, void* d_ws, size_t ws_size,
                              hipStream_t stream) {
    const float* seg = (const float*)d_in[0];
    // d_in[1] (prob) does not affect the reference output
    const int* gt  = (const int*)d_in[2];
    const int* gpn = (const int*)d_in[3];

    const int N = in_sizes[1];              // prob is (N,1)
    const int K = in_sizes[0] / N;          // 21
    const int GROWS = in_sizes[2] / N;      // 21
    const int NGROUP = (N + 63) >> 6;       // 4800 64-px groups

    int NBLK = MAXBLK;                      // 1152: g1 path absorbs the last 192
    const int minb = (NGROUP + 3) >> 2;
    if (NBLK > minb) NBLK = minb;
    const long long wcap = (long long)(ws_size / (TBL * sizeof(float)));
    if (NBLK > wcap) NBLK = (int)wcap;      // d_ws budget (observed ~256 MB)
    if (NBLK < 1) NBLK = 1;

    msk_main <<<NBLK, TPB, 0, stream>>>(seg, gt, (float*)d_ws,
                                        N, K, GROWS, NGROUP, NBLK);
    msk_final<<<K, 512, 0, stream>>>((const float*)d_ws, gpn, (int*)d_out,
                                     K, NBLK);
}

// Round 13
// 22.162 us; speedup vs baseline: 1.3528x; 1.0218x over previous
//
#include <hip/hip_runtime.h>

#define EPSF 1e-6f
#define TPB 256
#define KMAXC 21           // seg channels (K = 21)
#define NGR 21             // gt rows staged
#define RW 72              // bf16 row stride per wave slice (144 B; 16B-aligned frags)
#define SLICE (KMAXC * RW) // 1512 bf16 per matrix per wave
#define TBL 1024           // 32x32 cells per per-block table (4 KB stride)
#define MAXBLK 1152        // 32 K2-groups x 36 tables (exact 8-stream tiling)

typedef float  f32x4  __attribute__((ext_vector_type(4)));
typedef float  f32x16 __attribute__((ext_vector_type(16)));
typedef __bf16 bf16x8 __attribute__((ext_vector_type(8)));
typedef __bf16 bf16x4 __attribute__((ext_vector_type(4)));

struct GroupRegs { f32x4 s[6]; int4 g[6]; };

// issue all 12 vector loads for one 64-pixel group (stay in flight together)
__device__ __forceinline__ void issue_loads(const float* __restrict__ seg,
                                            const int* __restrict__ gt,
                                            int N, int GROWS, int p0, int lane,
                                            GroupRegs& r) {
    const f32x4* s4 = (const f32x4*)(seg + (size_t)p0 * KMAXC);
    #pragma unroll
    for (int q = 0; q < 6; ++q) {
        const int i4 = lane + (q << 6);            // f32x4 idx in [0,336)
        f32x4 v = {0.5f, 0.5f, 0.5f, 0.5f};
        if (i4 < 336) v = s4[i4];
        r.s[q] = v;
    }
    #pragma unroll
    for (int q = 0; q < 6; ++q) {
        const int i4 = lane + (q << 6);
        int4 gv = {0, 0, 0, 0};
        if (i4 < 336) {
            int row = i4 >> 4;                     // 0..20 (16 int4 per row)
            row = (row < GROWS) ? row : (GROWS - 1);
            gv = *(const int4*)(gt + (size_t)row * N + p0 + ((i4 & 15) << 2));
        }
        r.g[q] = gv;
    }
}

// log-odds + bf16 scatter to this wave's LDS slice
__device__ __forceinline__ void scatter_group(__bf16* dl, __bf16* ml, int lane,
                                              const GroupRegs& r) {
    #pragma unroll
    for (int q = 0; q < 6; ++q) {
        const int i4 = lane + (q << 6);
        if (i4 < 336) {
            const int lin = i4 << 2;
            int pix = lin / KMAXC;
            int k   = lin - pix * KMAXC;
            #pragma unroll
            for (int c = 0; c < 4; ++c) {
                const float s = r.s[q][c];
                const float dd = __log2f(s + EPSF) - __log2f(1.0f - s + EPSF);
                dl[k * RW + pix] = (__bf16)dd;
                if (++k == KMAXC) { k = 0; ++pix; }
            }
            const int row = i4 >> 4;
            bf16x4 mv;
            mv[0] = (__bf16)(float)(r.g[q].x != 0);
            mv[1] = (__bf16)(float)(r.g[q].y != 0);
            mv[2] = (__bf16)(float)(r.g[q].z != 0);
            mv[3] = (__bf16)(float)(r.g[q].w != 0);
            *(bf16x4*)(ml + row * RW + ((i4 & 15) << 2)) = mv;
        }
    }
}

// 4x MFMA over one 64-pixel group (K-dim = pixels)
__device__ __forceinline__ void mfma_group(const __bf16* dl, const __bf16* ml,
                                           int lane, int K, f32x16& acc) {
    const int r31  = lane & 31;
    const int rowA = (r31 < K)   ? r31 : (K - 1);   // clamp: dup rows discarded
    const int rowB = (r31 < NGR) ? r31 : (NGR - 1);
    const int off  = (lane >> 5) << 3;
    const __bf16* pa = dl + rowA * RW + off;
    const __bf16* pb = ml + rowB * RW + off;
    #pragma unroll
    for (int i = 0; i < 4; ++i) {
        const bf16x8 af = *(const bf16x8*)(pa + i * 16);
        const bf16x8 bf = *(const bf16x8*)(pb + i * 16);
        acc = __builtin_amdgcn_mfma_f32_32x32x16_bf16(af, bf, acc, 0, 0, 0);
    }
}

// generic per-element path (tail group / odd K)
__device__ __forceinline__ void generic_group(const float* __restrict__ seg,
                                              const int* __restrict__ gt,
                                              __bf16* dl, __bf16* ml, int lane,
                                              int N, int K, int GROWS, int p0) {
    for (int i = lane; i < K * 64; i += 64) {
        const int pix = i / K, k = i - pix * K;
        const float s = (p0 + pix < N) ? seg[(size_t)(p0 + pix) * K + k] : 0.5f;
        const float dd = __log2f(s + EPSF) - __log2f(1.0f - s + EPSF);
        if (k < KMAXC) dl[k * RW + pix] = (__bf16)dd;   // s=0.5 -> d=0 (inert)
    }
    for (int i = lane; i < NGR * 64; i += 64) {
        const int row = i >> 6, c = i & 63;
        int val = 0;
        if (row < GROWS && p0 + c < N) val = (gt[(size_t)row * N + p0 + c] != 0);
        ml[row * RW + c] = (__bf16)(float)val;
    }
}

// K1: A[k,g] = sum_n d[k,n]*gi[g,n]; wave-private; per-block private output
// table (no atom-RMW, no zero-init needed: every read cell written each call).
__global__ __launch_bounds__(TPB) void msk_main(
    const float* __restrict__ seg,   // (N, K) row-major
    const int* __restrict__ gt,      // (GROWS, N) row-major
    float* __restrict__ sums,        // NBLK x [TBL] f32 per-block tables
    int N, int K, int GROWS, int NGROUP, int NBLK)
{
    const int tid  = threadIdx.x;
    const int lane = tid & 63;
    const int wv   = tid >> 6;

    __shared__ union {
        __bf16 stage[4][2][SLICE];   // [wave][0=d rows [k][px], 1=mask rows [g][px]]
        float  red[4 * TBL];
    } u;

    f32x16 acc = {};
    __bf16* dl = u.stage[wv][0];
    __bf16* ml = u.stage[wv][1];

    const int W  = NBLK * 4;
    const int gw = (int)blockIdx.x * 4 + wv;

    if (K == KMAXC) {
        const int g0 = gw, g1 = gw + W;
        const bool f0 = (g0 < NGROUP) && ((g0 << 6) + 64 <= N);
        const bool f1 = (g1 < NGROUP) && ((g1 << 6) + 64 <= N);
        GroupRegs r0, r1;
        if (f0) issue_loads(seg, gt, N, GROWS, g0 << 6, lane, r0);
        if (f1) issue_loads(seg, gt, N, GROWS, g1 << 6, lane, r1);
        if (f0) { scatter_group(dl, ml, lane, r0); mfma_group(dl, ml, lane, K, acc); }
        if (f1) { scatter_group(dl, ml, lane, r1); mfma_group(dl, ml, lane, K, acc); }
        if (g0 < NGROUP && !f0) {
            generic_group(seg, gt, dl, ml, lane, N, K, GROWS, g0 << 6);
            mfma_group(dl, ml, lane, K, acc);
        }
        if (g1 < NGROUP && !f1) {
            generic_group(seg, gt, dl, ml, lane, N, K, GROWS, g1 << 6);
            mfma_group(dl, ml, lane, K, acc);
        }
        for (int gid = gw + 2 * W; gid < NGROUP; gid += W) {
            const int p0 = gid << 6;
            if (p0 + 64 <= N) {
                GroupRegs r;
                issue_loads(seg, gt, N, GROWS, p0, lane, r);
                scatter_group(dl, ml, lane, r);
            } else {
                generic_group(seg, gt, dl, ml, lane, N, K, GROWS, p0);
            }
            mfma_group(dl, ml, lane, K, acc);
        }
    } else {
        for (int gid = gw; gid < NGROUP; gid += W) {
            generic_group(seg, gt, dl, ml, lane, N, K, GROWS, gid << 6);
            mfma_group(dl, ml, lane, K, acc);
        }
    }

    // ---- cross-wave reduce via canonical LDS layout ----
    __syncthreads();
    {
        const int col = lane & 31;
        const int rhi = (lane >> 5) << 2;
        #pragma unroll
        for (int r = 0; r < 16; ++r) {
            const int row = (r & 3) + ((r >> 2) << 3) + rhi;   // verified C/D mapping
            u.red[wv * TBL + row * 32 + col] = acc[r];
        }
    }
    __syncthreads();

    // ---- private table write: live rows only (rows >= K never read by K2);
    //      relaxed agent-scope atomic stores (plain stores proved unsafe
    //      cross-kernel under graph replay) ----
    {
        float* stbl = sums + (size_t)blockIdx.x * TBL;
        const int live = K * 32;             // 672 cells
        for (int cell = tid; cell < live; cell += TPB) {
            const float v = u.red[cell] + u.red[TBL + cell]
                          + u.red[2 * TBL + cell] + u.red[3 * TBL + cell];
            __hip_atomic_store(&stbl[cell], v, __ATOMIC_RELAXED,
                               __HIP_MEMORY_SCOPE_AGENT);
        }
    }
}

// K2: block k reduces its row across all NBLK tables. 1024 threads, 32 table-
// groups; each group owns a CONTIGUOUS run of NBLK/32 tables walked with 8
// independent accumulator streams and unconditional affine loads (dependent
// depth ~NBLK/256, 8 loads in flight each).
__global__ __launch_bounds__(1024) void msk_final(
    const float* __restrict__ sums,
    const int* __restrict__ gpn,
    int* __restrict__ out,
    int K, int NBLK)
{
    const int G = *gpn;
    const int k = blockIdx.x;
    const int tid = threadIdx.x;
    const int col = tid & 31;
    const int grp = tid >> 5;            // 0..31 table-groups

    const int tpg = NBLK >> 5;           // tables per group (36 at NBLK=1152)
    const int t0  = grp * tpg;
    const size_t rowoff = (size_t)k * 32 + col;

    #define AL(T) __hip_atomic_load(&sums[(size_t)(T) * TBL + rowoff], \
                                    __ATOMIC_RELAXED, __HIP_MEMORY_SCOPE_AGENT)
    float v0 = 0.f, v1 = 0.f, v2 = 0.f, v3 = 0.f;
    float v4 = 0.f, v5 = 0.f, v6 = 0.f, v7 = 0.f;
    int i = 0;
    for (; i + 8 <= tpg; i += 8) {       // unconditional: 8 loads in flight
        v0 += AL(t0 + i + 0); v1 += AL(t0 + i + 1);
        v2 += AL(t0 + i + 2); v3 += AL(t0 + i + 3);
        v4 += AL(t0 + i + 4); v5 += AL(t0 + i + 5);
        v6 += AL(t0 + i + 6); v7 += AL(t0 + i + 7);
    }
    for (; i < tpg; ++i) v0 += AL(t0 + i);
    // leftover tables beyond 32*tpg (NBLK % 32 of them)
    if (grp < (NBLK & 31)) v1 += AL((NBLK & ~31) + grp);
    #undef AL
    const float vv = ((v0 + v1) + (v2 + v3)) + ((v4 + v5) + (v6 + v7));

    __shared__ float P[32][33];
    __shared__ float A[32];
    P[grp][col] = vv;
    __syncthreads();
    if (tid < 32) {
        float s = 0.f;
        #pragma unroll
        for (int g2 = 0; g2 < 32; ++g2) s += P[g2][tid];
        A[tid] = s;
    }
    __syncthreads();

    if (tid == 0) {
        const int GG = (G < 32) ? G : 32;
        float bv; int bg = 0;
        if (GG > 0) {
            bv = A[0];
            for (int g = 1; g < GG; ++g) {
                const float v = A[g];
                if (v > bv) { bv = v; bg = g; }   // strict '>' keeps first index
            }
        }
        out[k] = bg;
    }
}

extern "C" void kernel_launch(void* const* d_in, const int* in_sizes, int n_in,
                              void* d_out, int out_size, void* d_ws, size_t ws_size,
                              hipStream_t stream) {
    const float* seg = (const float*)d_in[0];
    // d_in[1] (prob) does not affect the reference output
    const int* gt  = (const int*)d_in[2];
    const int* gpn = (const int*)d_in[3];

    const int N = in_sizes[1];              // prob is (N,1)
    const int K = in_sizes[0] / N;          // 21
    const int GROWS = in_sizes[2] / N;      // 21
    const int NGROUP = (N + 63) >> 6;       // 4800 64-px groups

    int NBLK = MAXBLK;                      // 1152: g1 path absorbs the last 192
    const int minb = (NGROUP + 3) >> 2;
    if (NBLK > minb) NBLK = minb;
    const long long wcap = (long long)(ws_size / (TBL * sizeof(float)));
    if (NBLK > wcap) NBLK = (int)wcap;      // d_ws budget (observed ~256 MB)
    if (NBLK < 1) NBLK = 1;

    msk_main <<<NBLK, TPB, 0, stream>>>(seg, gt, (float*)d_ws,
                                        N, K, GROWS, NGROUP, NBLK);
    msk_final<<<K, 1024, 0, stream>>>((const float*)d_ws, gpn, (int*)d_out,
                                      K, NBLK);
}